// Round 3
// baseline (7277.221 us; speedup 1.0000x reference)
//
#include <hip/hip_runtime.h>
#include <hip/hip_bf16.h>

#define N_NODES 100000
#define N_EDGES 1600000
#define EMB 128
#define D2 256
#define EDGE_F 16
#define BN_EPS 1e-5f

// ---------------- static device scratch ----------------
// Every array read in a launch is fully (re)written earlier in that same
// launch, so stale state across calls cannot affect results.
__device__ int   g_deg[N_NODES];
__device__ int   g_rowoff[N_NODES + 1];
__device__ int   g_cur[N_NODES];
__device__ int   g_csr[N_EDGES];
__device__ float g_agg[N_NODES * EDGE_F];
__device__ float g_bnacc[2 * D2];      // [0:256) col sums, [256:512) col sumsq
__device__ float g_bncoef[2 * D2];     // [0:256) scale, [256:512) shift
__device__ float g_t[(size_t)N_NODES * D2];
__device__ float g_h1[(size_t)N_NODES * D2];
__device__ float g_xbuf[(size_t)N_NODES * EMB];

// ---------------- one-time preprocessing ----------------

__global__ void k_init() {
    int i = blockIdx.x * blockDim.x + threadIdx.x;
    int stride = gridDim.x * blockDim.x;
    for (int j = i; j < N_NODES; j += stride) g_deg[j] = 0;
    for (int j = i; j < N_NODES * EDGE_F; j += stride) g_agg[j] = 0.f;
}

// deg + per-node sum of edge_attr (exploits linearity of the edge embedding)
__global__ void k_edge(const int* __restrict__ ei, const float* __restrict__ ea) {
    int idx = blockIdx.x * blockDim.x + threadIdx.x;   // [0, E*16)
    if (idx >= N_EDGES * EDGE_F) return;
    int e = idx >> 4;
    int f = idx & 15;
    int d = ei[N_EDGES + e];
    if (f == 0) atomicAdd(&g_deg[d], 1);
    atomicAdd(&g_agg[d * EDGE_F + f], ea[idx]);
}

// exclusive scan of deg -> g_rowoff[0..N], g_cur = row starts
__global__ void k_scan() {
    __shared__ int s[1024];
    int tid = threadIdx.x;
    int carry = 0;
    if (tid == 0) g_rowoff[0] = 0;
    for (int base = 0; base < N_NODES; base += 1024) {
        int i = base + tid;
        int v = (i < N_NODES) ? g_deg[i] : 0;
        s[tid] = v;
        __syncthreads();
        for (int off = 1; off < 1024; off <<= 1) {
            int v2 = s[tid];
            if (tid >= off) v2 += s[tid - off];
            __syncthreads();
            s[tid] = v2;
            __syncthreads();
        }
        int incl = s[tid];
        if (i < N_NODES) {
            g_rowoff[i + 1] = carry + incl;
            g_cur[i] = carry + incl - v;
        }
        int tot = s[1023];
        __syncthreads();
        carry += tot;
    }
}

__global__ void k_fill(const int* __restrict__ ei) {
    int e = blockIdx.x * blockDim.x + threadIdx.x;
    if (e >= N_EDGES) return;
    int d = ei[N_EDGES + e];
    int pos = atomicAdd(&g_cur[d], 1);
    g_csr[pos] = ei[e];
}

// ---------------- per-layer kernels ----------------

// g_t[v, 0:128]   = x[v] + sum_{u in N(v)} x[u]
// g_t[v, 128:256] = agg_attr[v] @ EW_l^T + (deg[v]+1) * EB_l
// block = 256 threads = 2 nodes x 128 features. Block 0 zeroes bn accumulators.
template <bool FIRST>
__global__ void k_agg(const float* __restrict__ x0,
                      const float* __restrict__ EWl, const float* __restrict__ EBl) {
    if (blockIdx.x == 0) {
        g_bnacc[threadIdx.x] = 0.f;
        g_bnacc[threadIdx.x + 256] = 0.f;
    }
    int side = threadIdx.x >> 7;
    int f = threadIdx.x & 127;
    int v = blockIdx.x * 2 + side;
    __shared__ float sa[2][EDGE_F];
    if (f < EDGE_F) sa[side][f] = g_agg[v * EDGE_F + f];
    __syncthreads();
    float acc = FIRST ? x0[v * EMB + f] : g_xbuf[v * EMB + f];
    int r0 = g_rowoff[v], r1 = g_rowoff[v + 1];
    for (int i = r0; i < r1; ++i) {
        int u = g_csr[i];
        acc += FIRST ? x0[u * EMB + f] : g_xbuf[u * EMB + f];
    }
    g_t[v * D2 + f] = acc;
    float acc2 = 0.f;
#pragma unroll
    for (int k = 0; k < EDGE_F; ++k) acc2 += sa[side][k] * EWl[f * EDGE_F + k];
    acc2 += (float)(g_deg[v] + 1) * EBl[f];
    g_t[v * D2 + EMB + f] = acc2;
}

// h1 = t @ W1^T + b1   [N,256]x[256,256] -> f32
__global__ __launch_bounds__(256) void k_gemm1(const float* __restrict__ W1l,
                                               const float* __restrict__ B1l) {
    __shared__ float As[64][68];
    __shared__ float Bs[64][68];
    int tid = threadIdx.x;
    int tx = tid & 15, ty = tid >> 4;
    int ty4 = ty * 4, tx4 = tx * 4;
    int r0 = blockIdx.x * 64;
    int c0 = blockIdx.y * 64;
    float acc[4][4] = {};
    for (int kk = 0; kk < D2; kk += 64) {
        for (int idx = tid; idx < 4096; idx += 256) {
            int i = idx >> 6, j = idx & 63;
            int r = r0 + i;
            As[i][j] = (r < N_NODES) ? g_t[(size_t)r * D2 + kk + j] : 0.f;
        }
        for (int idx = tid; idx < 4096; idx += 256) {
            int c = idx >> 6, j = idx & 63;
            Bs[c][j] = W1l[(c0 + c) * D2 + kk + j];
        }
        __syncthreads();
#pragma unroll
        for (int k4 = 0; k4 < 64; k4 += 4) {
            float4 av[4], bv[4];
#pragma unroll
            for (int a = 0; a < 4; ++a) av[a] = *(const float4*)&As[ty4 + a][k4];
#pragma unroll
            for (int b = 0; b < 4; ++b) bv[b] = *(const float4*)&Bs[tx4 + b][k4];
#pragma unroll
            for (int a = 0; a < 4; ++a)
#pragma unroll
                for (int b = 0; b < 4; ++b)
                    acc[a][b] += av[a].x * bv[b].x + av[a].y * bv[b].y +
                                 av[a].z * bv[b].z + av[a].w * bv[b].w;
        }
        __syncthreads();
    }
#pragma unroll
    for (int a = 0; a < 4; ++a) {
        int r = r0 + ty4 + a;
        if (r < N_NODES) {
#pragma unroll
            for (int b = 0; b < 4; ++b) {
                int c = c0 + tx4 + b;
                g_h1[(size_t)r * D2 + c] = acc[a][b] + B1l[c];
            }
        }
    }
}

// column sums / sums of squares of h1 (for BN batch stats)
__global__ void k_stats() {
    int c = threadIdx.x;
    float s = 0.f, q = 0.f;
    for (int r = blockIdx.x; r < N_NODES; r += gridDim.x) {
        float v = g_h1[(size_t)r * D2 + c];
        s += v;
        q += v * v;
    }
    atomicAdd(&g_bnacc[c], s);
    atomicAdd(&g_bnacc[D2 + c], q);
}

__global__ void k_bnfin(const float* __restrict__ BNWl, const float* __restrict__ BNBl) {
    int c = threadIdx.x;
    float inv_n = 1.f / (float)N_NODES;
    float mean = g_bnacc[c] * inv_n;
    float var = g_bnacc[D2 + c] * inv_n - mean * mean;
    float sc = BNWl[c] * rsqrtf(var + BN_EPS);
    g_bncoef[c] = sc;
    g_bncoef[D2 + c] = BNBl[c] - mean * sc;
}

// out = [relu]( relu(h1*scale+shift) @ W2^T + b2 )
template <bool LAST>
__global__ __launch_bounds__(256) void k_gemm2(const float* __restrict__ W2l,
                                               const float* __restrict__ B2l,
                                               float* __restrict__ out) {
    __shared__ float As[64][68];
    __shared__ float Bs[64][68];
    __shared__ float sc[2 * D2];
    int tid = threadIdx.x;
    sc[tid] = g_bncoef[tid];
    sc[tid + 256] = g_bncoef[tid + 256];
    __syncthreads();
    int tx = tid & 15, ty = tid >> 4;
    int ty4 = ty * 4, tx4 = tx * 4;
    int r0 = blockIdx.x * 64;
    int c0 = blockIdx.y * 64;
    float acc[4][4] = {};
    for (int kk = 0; kk < D2; kk += 64) {
        for (int idx = tid; idx < 4096; idx += 256) {
            int i = idx >> 6, j = idx & 63;
            int r = r0 + i;
            float v = 0.f;
            if (r < N_NODES) {
                v = g_h1[(size_t)r * D2 + kk + j];
                v = fmaxf(v * sc[kk + j] + sc[D2 + kk + j], 0.f);
            }
            As[i][j] = v;
        }
        for (int idx = tid; idx < 4096; idx += 256) {
            int c = idx >> 6, j = idx & 63;
            Bs[c][j] = W2l[(c0 + c) * D2 + kk + j];
        }
        __syncthreads();
#pragma unroll
        for (int k4 = 0; k4 < 64; k4 += 4) {
            float4 av[4], bv[4];
#pragma unroll
            for (int a = 0; a < 4; ++a) av[a] = *(const float4*)&As[ty4 + a][k4];
#pragma unroll
            for (int b = 0; b < 4; ++b) bv[b] = *(const float4*)&Bs[tx4 + b][k4];
#pragma unroll
            for (int a = 0; a < 4; ++a)
#pragma unroll
                for (int b = 0; b < 4; ++b)
                    acc[a][b] += av[a].x * bv[b].x + av[a].y * bv[b].y +
                                 av[a].z * bv[b].z + av[a].w * bv[b].w;
        }
        __syncthreads();
    }
#pragma unroll
    for (int a = 0; a < 4; ++a) {
        int r = r0 + ty4 + a;
        if (r < N_NODES) {
#pragma unroll
            for (int b = 0; b < 4; ++b) {
                int c = c0 + tx4 + b;
                float v = acc[a][b] + B2l[c];
                if (LAST) {
                    out[(size_t)r * EMB + c] = v;
                } else {
                    g_xbuf[(size_t)r * EMB + c] = fmaxf(v, 0.f);
                }
            }
        }
    }
}

extern "C" void kernel_launch(void* const* d_in, const int* in_sizes, int n_in,
                              void* d_out, int out_size, void* d_ws, size_t ws_size,
                              hipStream_t stream) {
    const float* x0 = (const float*)d_in[0];
    const float* ea = (const float*)d_in[1];
    const float* W1 = (const float*)d_in[2];
    const float* B1 = (const float*)d_in[3];
    const float* BNW = (const float*)d_in[4];
    const float* BNB = (const float*)d_in[5];
    const float* W2 = (const float*)d_in[6];
    const float* B2 = (const float*)d_in[7];
    const float* EW = (const float*)d_in[8];
    const float* EB = (const float*)d_in[9];
    const int* ei = (const int*)d_in[10];

    k_init<<<4096, 256, 0, stream>>>();
    k_edge<<<(N_EDGES * EDGE_F + 255) / 256, 256, 0, stream>>>(ei, ea);
    k_scan<<<1, 1024, 0, stream>>>();
    k_fill<<<(N_EDGES + 255) / 256, 256, 0, stream>>>(ei);

    const int GM = (N_NODES + 63) / 64;  // 1563
    for (int l = 0; l < 5; ++l) {
        const float* W1l = W1 + (size_t)l * D2 * D2;
        const float* B1l = B1 + (size_t)l * D2;
        const float* BNWl = BNW + (size_t)l * D2;
        const float* BNBl = BNB + (size_t)l * D2;
        const float* W2l = W2 + (size_t)l * EMB * D2;
        const float* B2l = B2 + (size_t)l * EMB;
        const float* EWl = EW + (size_t)l * EMB * EDGE_F;
        const float* EBl = EB + (size_t)l * EMB;

        if (l == 0)
            k_agg<true><<<N_NODES / 2, 256, 0, stream>>>(x0, EWl, EBl);
        else
            k_agg<false><<<N_NODES / 2, 256, 0, stream>>>(nullptr, EWl, EBl);

        k_gemm1<<<dim3(GM, 4), 256, 0, stream>>>(W1l, B1l);
        k_stats<<<512, 256, 0, stream>>>();
        k_bnfin<<<1, 256, 0, stream>>>(BNWl, BNBl);

        if (l < 4)
            k_gemm2<false><<<dim3(GM, 2), 256, 0, stream>>>(W2l, B2l, nullptr);
        else
            k_gemm2<true><<<dim3(GM, 2), 256, 0, stream>>>(W2l, B2l, (float*)d_out);
    }
}

// Round 4
// 3072.513 us; speedup vs baseline: 2.3685x; 2.3685x over previous
//
#include <hip/hip_runtime.h>
#include <hip/hip_bf16.h>

#define N_NODES 100000
#define N_EDGES 1600000
#define EMB 128
#define D2 256
#define EDGE_F 16
#define BN_EPS 1e-5f
#define BK 64
#define SK 72   // LDS row stride (elements): 144 B = 9*16 B -> 2-way max conflict

typedef __hip_bfloat16 bf16;
typedef __attribute__((ext_vector_type(8))) short bf16x8;
typedef __attribute__((ext_vector_type(4))) float f32x4;

__device__ __forceinline__ bf16 f2b(float v) { return __float2bfloat16(v); }
__device__ __forceinline__ unsigned short f2bu(float v) {
    bf16 b = __float2bfloat16(v);
    return *(unsigned short*)&b;
}

// ---------------- static device scratch ----------------
__device__ int   g_deg[N_NODES];
__device__ int   g_rowoff[N_NODES + 1];
__device__ int   g_cur[N_NODES];
__device__ int   g_csr[N_EDGES];
__device__ float g_agg[N_NODES * EDGE_F];
__device__ float g_bnacc[2 * D2];
__device__ float g_bncoef[2 * D2];
__device__ bf16  g_t[(size_t)N_NODES * D2];     // GEMM1 A operand (bf16)
__device__ float g_h1[(size_t)N_NODES * D2];    // fp32 for exact BN stats
__device__ float g_xbuf[(size_t)N_NODES * EMB];
__device__ bf16  g_w1b[D2 * D2];
__device__ bf16  g_w2b[EMB * D2];

// ---------------- one-time preprocessing ----------------

__global__ void k_init() {
    int i = blockIdx.x * blockDim.x + threadIdx.x;
    int stride = gridDim.x * blockDim.x;
    for (int j = i; j < N_NODES; j += stride) g_deg[j] = 0;
    for (int j = i; j < N_NODES * EDGE_F; j += stride) g_agg[j] = 0.f;
}

__global__ void k_edge(const int* __restrict__ ei, const float* __restrict__ ea) {
    int idx = blockIdx.x * blockDim.x + threadIdx.x;
    if (idx >= N_EDGES * EDGE_F) return;
    int e = idx >> 4;
    int f = idx & 15;
    int d = ei[N_EDGES + e];
    if (f == 0) atomicAdd(&g_deg[d], 1);
    atomicAdd(&g_agg[d * EDGE_F + f], ea[idx]);
}

__global__ void k_scan() {
    __shared__ int s[1024];
    int tid = threadIdx.x;
    int carry = 0;
    if (tid == 0) g_rowoff[0] = 0;
    for (int base = 0; base < N_NODES; base += 1024) {
        int i = base + tid;
        int v = (i < N_NODES) ? g_deg[i] : 0;
        s[tid] = v;
        __syncthreads();
        for (int off = 1; off < 1024; off <<= 1) {
            int v2 = s[tid];
            if (tid >= off) v2 += s[tid - off];
            __syncthreads();
            s[tid] = v2;
            __syncthreads();
        }
        int incl = s[tid];
        if (i < N_NODES) {
            g_rowoff[i + 1] = carry + incl;
            g_cur[i] = carry + incl - v;
        }
        int tot = s[1023];
        __syncthreads();
        carry += tot;
    }
}

__global__ void k_fill(const int* __restrict__ ei) {
    int e = blockIdx.x * blockDim.x + threadIdx.x;
    if (e >= N_EDGES) return;
    int d = ei[N_EDGES + e];
    int pos = atomicAdd(&g_cur[d], 1);
    g_csr[pos] = ei[e];
}

// convert this layer's weights to bf16
__global__ void k_cvt(const float* __restrict__ W1l, const float* __restrict__ W2l) {
    int i = blockIdx.x * blockDim.x + threadIdx.x;
    if (i < D2 * D2) g_w1b[i] = f2b(W1l[i]);
    int j = i - D2 * D2;
    if (j >= 0 && j < EMB * D2) g_w2b[j] = f2b(W2l[j]);
}

// ---------------- per-layer kernels ----------------

// g_t[v,0:128] = x[v] + sum_{u in N(v)} x[u];  g_t[v,128:256] = edge part
template <bool FIRST>
__global__ void k_agg(const float* __restrict__ x0,
                      const float* __restrict__ EWl, const float* __restrict__ EBl) {
    if (blockIdx.x == 0) {
        g_bnacc[threadIdx.x] = 0.f;
        g_bnacc[threadIdx.x + 256] = 0.f;
    }
    int side = threadIdx.x >> 7;
    int f = threadIdx.x & 127;
    int v = blockIdx.x * 2 + side;
    __shared__ float sa[2][EDGE_F];
    if (f < EDGE_F) sa[side][f] = g_agg[v * EDGE_F + f];
    __syncthreads();
    float acc = FIRST ? x0[v * EMB + f] : g_xbuf[(size_t)v * EMB + f];
    int r0 = g_rowoff[v], r1 = g_rowoff[v + 1];
    for (int i = r0; i < r1; ++i) {
        int u = g_csr[i];
        acc += FIRST ? x0[u * EMB + f] : g_xbuf[(size_t)u * EMB + f];
    }
    g_t[(size_t)v * D2 + f] = f2b(acc);
    float acc2 = 0.f;
#pragma unroll
    for (int k = 0; k < EDGE_F; ++k) acc2 += sa[side][k] * EWl[f * EDGE_F + k];
    acc2 += (float)(g_deg[v] + 1) * EBl[f];
    g_t[(size_t)v * D2 + EMB + f] = f2b(acc2);
}

// h1 = t @ W1^T + b1 via bf16 MFMA, fp32 out.
// block 256 thr = 4 waves; tile 128x128; wave w -> rows (w>>1)*64, cols (w&1)*64.
__global__ __launch_bounds__(256) void k_gemm1(const float* __restrict__ B1l) {
    __shared__ __align__(16) short sA[128 * SK];
    __shared__ __align__(16) short sB[128 * SK];
    int tid = threadIdx.x;
    int r0 = blockIdx.x * 128;
    int c0 = blockIdx.y * 128;
    int w = tid >> 6, lane = tid & 63;
    int wr = (w >> 1) * 64, wc = (w & 1) * 64;
    int ln = lane & 15, lq = lane >> 4;
    f32x4 acc[4][4] = {};
    const uint4* gt = (const uint4*)g_t;     // row stride 32 uint4
    const uint4* gw = (const uint4*)g_w1b;
    for (int kk = 0; kk < D2; kk += BK) {
#pragma unroll
        for (int t = 0; t < 4; ++t) {
            int idx = tid + t * 256;
            int row = idx >> 3, seg = idx & 7;
            int r = r0 + row;
            uint4 val = make_uint4(0, 0, 0, 0);
            if (r < N_NODES) val = gt[(size_t)r * 32 + (kk >> 3) + seg];
            *(uint4*)&sA[row * SK + seg * 8] = val;
        }
#pragma unroll
        for (int t = 0; t < 4; ++t) {
            int idx = tid + t * 256;
            int row = idx >> 3, seg = idx & 7;
            *(uint4*)&sB[row * SK + seg * 8] = gw[(size_t)(c0 + row) * 32 + (kk >> 3) + seg];
        }
        __syncthreads();
#pragma unroll
        for (int k0 = 0; k0 < BK; k0 += 32) {
            bf16x8 af[4], bg[4];
#pragma unroll
            for (int a = 0; a < 4; ++a)
                af[a] = *(const bf16x8*)&sA[(wr + a * 16 + ln) * SK + k0 + lq * 8];
#pragma unroll
            for (int b = 0; b < 4; ++b)
                bg[b] = *(const bf16x8*)&sB[(wc + b * 16 + ln) * SK + k0 + lq * 8];
#pragma unroll
            for (int a = 0; a < 4; ++a)
#pragma unroll
                for (int b = 0; b < 4; ++b)
                    acc[a][b] = __builtin_amdgcn_mfma_f32_16x16x32_bf16(af[a], bg[b],
                                                                        acc[a][b], 0, 0, 0);
        }
        __syncthreads();
    }
#pragma unroll
    for (int a = 0; a < 4; ++a) {
#pragma unroll
        for (int r = 0; r < 4; ++r) {
            int row = r0 + wr + a * 16 + lq * 4 + r;
            if (row < N_NODES) {
#pragma unroll
                for (int b = 0; b < 4; ++b) {
                    int col = c0 + wc + b * 16 + ln;
                    g_h1[(size_t)row * D2 + col] = acc[a][b][r] + B1l[col];
                }
            }
        }
    }
}

__global__ void k_stats() {
    int c = threadIdx.x;
    float s = 0.f, q = 0.f;
    for (int r = blockIdx.x; r < N_NODES; r += gridDim.x) {
        float v = g_h1[(size_t)r * D2 + c];
        s += v;
        q += v * v;
    }
    atomicAdd(&g_bnacc[c], s);
    atomicAdd(&g_bnacc[D2 + c], q);
}

__global__ void k_bnfin(const float* __restrict__ BNWl, const float* __restrict__ BNBl) {
    int c = threadIdx.x;
    float inv_n = 1.f / (float)N_NODES;
    float mean = g_bnacc[c] * inv_n;
    float var = g_bnacc[D2 + c] * inv_n - mean * mean;
    float sc = BNWl[c] * rsqrtf(var + BN_EPS);
    g_bncoef[c] = sc;
    g_bncoef[D2 + c] = BNBl[c] - mean * sc;
}

// out = [relu]( relu(h1*scale+shift) @ W2^T + b2 ) via bf16 MFMA.
// BN+ReLU+bf16-convert fused into the A staging pass.
template <bool LAST>
__global__ __launch_bounds__(256) void k_gemm2(const float* __restrict__ B2l,
                                               float* __restrict__ out) {
    __shared__ __align__(16) short sA[128 * SK];
    __shared__ __align__(16) short sB[128 * SK];
    __shared__ __align__(16) float sC[2 * D2];
    int tid = threadIdx.x;
    sC[tid] = g_bncoef[tid];
    sC[tid + 256] = g_bncoef[tid + 256];
    __syncthreads();
    int r0 = blockIdx.x * 128;
    int w = tid >> 6, lane = tid & 63;
    int wr = (w >> 1) * 64, wc = (w & 1) * 64;
    int ln = lane & 15, lq = lane >> 4;
    f32x4 acc[4][4] = {};
    const uint4* gw = (const uint4*)g_w2b;   // 128 rows x 32 uint4
    for (int kk = 0; kk < D2; kk += BK) {
        // A: 128 rows x 64 fp32 -> BN+relu -> bf16
#pragma unroll
        for (int t = 0; t < 8; ++t) {
            int idx = tid + t * 256;
            int row = idx >> 4, seg = idx & 15;
            int r = r0 + row;
            int k = kk + seg * 4;
            ushort4 o = make_ushort4(0, 0, 0, 0);
            if (r < N_NODES) {
                float4 v = *(const float4*)&g_h1[(size_t)r * D2 + k];
                float4 s = *(const float4*)&sC[k];
                float4 h = *(const float4*)&sC[D2 + k];
                o.x = f2bu(fmaxf(v.x * s.x + h.x, 0.f));
                o.y = f2bu(fmaxf(v.y * s.y + h.y, 0.f));
                o.z = f2bu(fmaxf(v.z * s.z + h.z, 0.f));
                o.w = f2bu(fmaxf(v.w * s.w + h.w, 0.f));
            }
            *(ushort4*)&sA[row * SK + seg * 4] = o;
        }
#pragma unroll
        for (int t = 0; t < 4; ++t) {
            int idx = tid + t * 256;
            int row = idx >> 3, seg = idx & 7;
            *(uint4*)&sB[row * SK + seg * 8] = gw[(size_t)row * 32 + (kk >> 3) + seg];
        }
        __syncthreads();
#pragma unroll
        for (int k0 = 0; k0 < BK; k0 += 32) {
            bf16x8 af[4], bg[4];
#pragma unroll
            for (int a = 0; a < 4; ++a)
                af[a] = *(const bf16x8*)&sA[(wr + a * 16 + ln) * SK + k0 + lq * 8];
#pragma unroll
            for (int b = 0; b < 4; ++b)
                bg[b] = *(const bf16x8*)&sB[(wc + b * 16 + ln) * SK + k0 + lq * 8];
#pragma unroll
            for (int a = 0; a < 4; ++a)
#pragma unroll
                for (int b = 0; b < 4; ++b)
                    acc[a][b] = __builtin_amdgcn_mfma_f32_16x16x32_bf16(af[a], bg[b],
                                                                        acc[a][b], 0, 0, 0);
        }
        __syncthreads();
    }
#pragma unroll
    for (int a = 0; a < 4; ++a) {
#pragma unroll
        for (int r = 0; r < 4; ++r) {
            int row = r0 + wr + a * 16 + lq * 4 + r;
            if (row < N_NODES) {
#pragma unroll
                for (int b = 0; b < 4; ++b) {
                    int col = wc + b * 16 + ln;   // 0..127
                    float v = acc[a][b][r] + B2l[col];
                    if (LAST) out[(size_t)row * EMB + col] = v;
                    else      g_xbuf[(size_t)row * EMB + col] = fmaxf(v, 0.f);
                }
            }
        }
    }
}

extern "C" void kernel_launch(void* const* d_in, const int* in_sizes, int n_in,
                              void* d_out, int out_size, void* d_ws, size_t ws_size,
                              hipStream_t stream) {
    const float* x0 = (const float*)d_in[0];
    const float* ea = (const float*)d_in[1];
    const float* W1 = (const float*)d_in[2];
    const float* B1 = (const float*)d_in[3];
    const float* BNW = (const float*)d_in[4];
    const float* BNB = (const float*)d_in[5];
    const float* W2 = (const float*)d_in[6];
    const float* B2 = (const float*)d_in[7];
    const float* EW = (const float*)d_in[8];
    const float* EB = (const float*)d_in[9];
    const int* ei = (const int*)d_in[10];

    k_init<<<4096, 256, 0, stream>>>();
    k_edge<<<(N_EDGES * EDGE_F + 255) / 256, 256, 0, stream>>>(ei, ea);
    k_scan<<<1, 1024, 0, stream>>>();
    k_fill<<<(N_EDGES + 255) / 256, 256, 0, stream>>>(ei);

    const int GB = (N_NODES + 127) / 128;   // 782
    for (int l = 0; l < 5; ++l) {
        const float* W1l = W1 + (size_t)l * D2 * D2;
        const float* B1l = B1 + (size_t)l * D2;
        const float* BNWl = BNW + (size_t)l * D2;
        const float* BNBl = BNB + (size_t)l * D2;
        const float* W2l = W2 + (size_t)l * EMB * D2;
        const float* B2l = B2 + (size_t)l * EMB;
        const float* EWl = EW + (size_t)l * EMB * EDGE_F;
        const float* EBl = EB + (size_t)l * EMB;

        k_cvt<<<(D2 * D2 + EMB * D2 + 255) / 256, 256, 0, stream>>>(W1l, W2l);

        if (l == 0)
            k_agg<true><<<N_NODES / 2, 256, 0, stream>>>(x0, EWl, EBl);
        else
            k_agg<false><<<N_NODES / 2, 256, 0, stream>>>(nullptr, EWl, EBl);

        k_gemm1<<<dim3(GB, 2), 256, 0, stream>>>(B1l);
        k_stats<<<512, 256, 0, stream>>>();
        k_bnfin<<<1, 256, 0, stream>>>(BNWl, BNBl);

        if (l < 4)
            k_gemm2<false><<<dim3(GB, 1), 256, 0, stream>>>(B2l, nullptr);
        else
            k_gemm2<true><<<dim3(GB, 1), 256, 0, stream>>>(B2l, (float*)d_out);
    }
}

// Round 5
// 1954.718 us; speedup vs baseline: 3.7229x; 1.5718x over previous
//
#include <hip/hip_runtime.h>
#include <hip/hip_bf16.h>

#define N_NODES 100000
#define N_EDGES 1600000
#define EMB 128
#define D2 256
#define EDGE_F 16
#define BN_EPS 1e-5f
#define BK 64
#define SK 72   // LDS row stride (elements): 144 B -> max 2-way conflict (free)
#define NSCB 98 // scan blocks = ceil(N/1024)

typedef __hip_bfloat16 bf16;
typedef __attribute__((ext_vector_type(8))) short bf16x8;
typedef __attribute__((ext_vector_type(4))) float f32x4;

__device__ __forceinline__ bf16 f2b(float v) { return __float2bfloat16(v); }
__device__ __forceinline__ unsigned short f2bu(float v) {
    bf16 b = __float2bfloat16(v);
    return *(unsigned short*)&b;
}

// ---------------- static device scratch ----------------
__device__ int   g_deg[N_NODES];
__device__ int   g_rowoff[N_NODES + 1];
__device__ int   g_cur[N_NODES];
__device__ int   g_csr[N_EDGES];
__device__ int   g_blksum[NSCB];
__device__ int   g_blkoff[NSCB];
__device__ float g_agg[N_NODES * EDGE_F];
__device__ float g_bnacc[2 * D2];
__device__ float g_bncoef[2 * D2];
__device__ bf16  g_t[(size_t)N_NODES * D2];
__device__ float g_h1[(size_t)N_NODES * D2];
__device__ float g_xbuf[(size_t)N_NODES * EMB];
__device__ bf16  g_w1b[D2 * D2];
__device__ bf16  g_w2b[EMB * D2];

// ---------------- one-time preprocessing ----------------

__global__ void k_init() {
    int i = blockIdx.x * blockDim.x + threadIdx.x;
    int stride = gridDim.x * blockDim.x;
    for (int j = i; j < N_NODES; j += stride) g_deg[j] = 0;
    for (int j = i; j < N_NODES * EDGE_F; j += stride) g_agg[j] = 0.f;
}

__global__ void k_edge(const int* __restrict__ ei, const float* __restrict__ ea) {
    int idx = blockIdx.x * blockDim.x + threadIdx.x;
    if (idx >= N_EDGES * EDGE_F) return;
    int e = idx >> 4;
    int f = idx & 15;
    int d = ei[N_EDGES + e];
    if (f == 0) atomicAdd(&g_deg[d], 1);
    atomicAdd(&g_agg[d * EDGE_F + f], ea[idx]);
}

// hierarchical scan: per-block inclusive scan
__global__ void k_scan1() {
    __shared__ int s[1024];
    int tid = threadIdx.x;
    int i = blockIdx.x * 1024 + tid;
    int v = (i < N_NODES) ? g_deg[i] : 0;
    s[tid] = v;
    __syncthreads();
    for (int off = 1; off < 1024; off <<= 1) {
        int v2 = s[tid];
        if (tid >= off) v2 += s[tid - off];
        __syncthreads();
        s[tid] = v2;
        __syncthreads();
    }
    if (i < N_NODES) g_rowoff[i + 1] = s[tid];
    if (tid == 1023) g_blksum[blockIdx.x] = s[1023];
}

__global__ void k_scan2() {
    __shared__ int s[128];
    int tid = threadIdx.x;
    int v = (tid < NSCB) ? g_blksum[tid] : 0;
    s[tid] = v;
    __syncthreads();
    for (int off = 1; off < 128; off <<= 1) {
        int v2 = s[tid];
        if (tid >= off) v2 += s[tid - off];
        __syncthreads();
        s[tid] = v2;
        __syncthreads();
    }
    if (tid < NSCB) g_blkoff[tid] = s[tid] - v;   // exclusive
}

__global__ void k_scan3() {
    int i = blockIdx.x * blockDim.x + threadIdx.x;
    if (i == 0) g_rowoff[0] = 0;
    if (i < N_NODES) {
        int r = g_rowoff[i + 1] + g_blkoff[i >> 10];
        g_rowoff[i + 1] = r;
        g_cur[i] = r - g_deg[i];
    }
}

__global__ void k_fill(const int* __restrict__ ei) {
    int e = blockIdx.x * blockDim.x + threadIdx.x;
    if (e >= N_EDGES) return;
    int d = ei[N_EDGES + e];
    int pos = atomicAdd(&g_cur[d], 1);
    g_csr[pos] = ei[e];
}

__global__ void k_cvt(const float* __restrict__ W1l, const float* __restrict__ W2l) {
    int i = blockIdx.x * blockDim.x + threadIdx.x;
    if (i < D2 * D2) g_w1b[i] = f2b(W1l[i]);
    int j = i - D2 * D2;
    if (j >= 0 && j < EMB * D2) g_w2b[j] = f2b(W2l[j]);
}

// ---------------- per-layer kernels ----------------

// 32-lane group per node (8 nodes/block); lane owns 4 features (float4).
// Neighbor indices loaded coalesced then shfl-broadcast; gather unrolled x4.
template <bool FIRST>
__global__ __launch_bounds__(256) void k_agg(const float* __restrict__ x0,
                                             const float* __restrict__ EWl,
                                             const float* __restrict__ EBl) {
    int tid = threadIdx.x;
    if (blockIdx.x == 0) {
        g_bnacc[tid] = 0.f;
        g_bnacc[tid + 256] = 0.f;
    }
    int g = tid >> 5, lane32 = tid & 31;
    int v = blockIdx.x * 8 + g;
    __shared__ float sa[8][EDGE_F];
    if (lane32 < EDGE_F) sa[g][lane32] = g_agg[v * EDGE_F + lane32];
    __syncthreads();

    const float* src = FIRST ? x0 : g_xbuf;
    int r0 = g_rowoff[v], r1 = g_rowoff[v + 1];
    int deg = r1 - r0;
    float4 acc = *(const float4*)&src[(size_t)v * EMB + lane32 * 4];

    for (int base = r0; base < r1; base += 32) {
        int nb = r1 - base;
        if (nb > 32) nb = 32;
        int idx = (lane32 < nb) ? g_csr[base + lane32] : 0;
        int j = 0;
        for (; j + 4 <= nb; j += 4) {
            int u0 = __shfl(idx, j, 32);
            int u1 = __shfl(idx, j + 1, 32);
            int u2 = __shfl(idx, j + 2, 32);
            int u3 = __shfl(idx, j + 3, 32);
            float4 a0 = *(const float4*)&src[(size_t)u0 * EMB + lane32 * 4];
            float4 a1 = *(const float4*)&src[(size_t)u1 * EMB + lane32 * 4];
            float4 a2 = *(const float4*)&src[(size_t)u2 * EMB + lane32 * 4];
            float4 a3 = *(const float4*)&src[(size_t)u3 * EMB + lane32 * 4];
            acc.x += (a0.x + a1.x) + (a2.x + a3.x);
            acc.y += (a0.y + a1.y) + (a2.y + a3.y);
            acc.z += (a0.z + a1.z) + (a2.z + a3.z);
            acc.w += (a0.w + a1.w) + (a2.w + a3.w);
        }
        for (; j < nb; ++j) {
            int u = __shfl(idx, j, 32);
            float4 a0 = *(const float4*)&src[(size_t)u * EMB + lane32 * 4];
            acc.x += a0.x; acc.y += a0.y; acc.z += a0.z; acc.w += a0.w;
        }
    }
    ushort4 o;
    o.x = f2bu(acc.x); o.y = f2bu(acc.y); o.z = f2bu(acc.z); o.w = f2bu(acc.w);
    *(ushort4*)&g_t[(size_t)v * D2 + lane32 * 4] = o;

    // edge-embedding half: t[v,128+f] = sum_k agg[v,k]*EW[f,k] + (deg+1)*EB[f]
    float dp1 = (float)(deg + 1);
    ushort4 o2;
    unsigned short* op = (unsigned short*)&o2;
#pragma unroll
    for (int cc = 0; cc < 4; ++cc) {
        int f = lane32 * 4 + cc;
        float s2 = 0.f;
#pragma unroll
        for (int k = 0; k < EDGE_F; ++k) s2 += sa[g][k] * EWl[f * EDGE_F + k];
        s2 += dp1 * EBl[f];
        op[cc] = f2bu(s2);
    }
    *(ushort4*)&g_t[(size_t)v * D2 + EMB + lane32 * 4] = o2;
}

// h1 = t @ W1^T + b1 via bf16 MFMA; BN column sums/sumsq fused into epilogue.
__global__ __launch_bounds__(256) void k_gemm1(const float* __restrict__ B1l) {
    __shared__ __align__(16) short sA[128 * SK];
    __shared__ __align__(16) short sB[128 * SK];
    int tid = threadIdx.x;
    int r0 = blockIdx.x * 128;
    int c0 = blockIdx.y * 128;
    int w = tid >> 6, lane = tid & 63;
    int wr = (w >> 1) * 64, wc = (w & 1) * 64;
    int ln = lane & 15, lq = lane >> 4;
    f32x4 acc[4][4] = {};
    const uint4* gt = (const uint4*)g_t;
    const uint4* gw = (const uint4*)g_w1b;
    for (int kk = 0; kk < D2; kk += BK) {
#pragma unroll
        for (int t = 0; t < 4; ++t) {
            int idx = tid + t * 256;
            int row = idx >> 3, seg = idx & 7;
            int r = r0 + row;
            uint4 val = make_uint4(0, 0, 0, 0);
            if (r < N_NODES) val = gt[(size_t)r * 32 + (kk >> 3) + seg];
            *(uint4*)&sA[row * SK + seg * 8] = val;
        }
#pragma unroll
        for (int t = 0; t < 4; ++t) {
            int idx = tid + t * 256;
            int row = idx >> 3, seg = idx & 7;
            *(uint4*)&sB[row * SK + seg * 8] = gw[(size_t)(c0 + row) * 32 + (kk >> 3) + seg];
        }
        __syncthreads();
#pragma unroll
        for (int k0 = 0; k0 < BK; k0 += 32) {
            bf16x8 af[4], bg[4];
#pragma unroll
            for (int a = 0; a < 4; ++a)
                af[a] = *(const bf16x8*)&sA[(wr + a * 16 + ln) * SK + k0 + lq * 8];
#pragma unroll
            for (int b = 0; b < 4; ++b)
                bg[b] = *(const bf16x8*)&sB[(wc + b * 16 + ln) * SK + k0 + lq * 8];
#pragma unroll
            for (int a = 0; a < 4; ++a)
#pragma unroll
                for (int b = 0; b < 4; ++b)
                    acc[a][b] = __builtin_amdgcn_mfma_f32_16x16x32_bf16(af[a], bg[b],
                                                                        acc[a][b], 0, 0, 0);
        }
        __syncthreads();
    }
    float sacc[4] = {0.f, 0.f, 0.f, 0.f};
    float qacc[4] = {0.f, 0.f, 0.f, 0.f};
#pragma unroll
    for (int a = 0; a < 4; ++a) {
#pragma unroll
        for (int r = 0; r < 4; ++r) {
            int row = r0 + wr + a * 16 + lq * 4 + r;
            if (row < N_NODES) {
#pragma unroll
                for (int b = 0; b < 4; ++b) {
                    int col = c0 + wc + b * 16 + ln;
                    float h = acc[a][b][r] + B1l[col];
                    g_h1[(size_t)row * D2 + col] = h;
                    sacc[b] += h;
                    qacc[b] += h * h;
                }
            }
        }
    }
#pragma unroll
    for (int b = 0; b < 4; ++b) {
        float s = sacc[b], q = qacc[b];
        s += __shfl_xor(s, 16); q += __shfl_xor(q, 16);
        s += __shfl_xor(s, 32); q += __shfl_xor(q, 32);
        if (lq == 0) {
            int col = c0 + wc + b * 16 + ln;
            atomicAdd(&g_bnacc[col], s);
            atomicAdd(&g_bnacc[D2 + col], q);
        }
    }
}

__global__ void k_bnfin(const float* __restrict__ BNWl, const float* __restrict__ BNBl) {
    int c = threadIdx.x;
    float inv_n = 1.f / (float)N_NODES;
    float mean = g_bnacc[c] * inv_n;
    float var = g_bnacc[D2 + c] * inv_n - mean * mean;
    float sc = BNWl[c] * rsqrtf(var + BN_EPS);
    g_bncoef[c] = sc;
    g_bncoef[D2 + c] = BNBl[c] - mean * sc;
}

// out = [relu]( relu(h1*scale+shift) @ W2^T + b2 ) via bf16 MFMA.
template <bool LAST>
__global__ __launch_bounds__(256) void k_gemm2(const float* __restrict__ B2l,
                                               float* __restrict__ out) {
    __shared__ __align__(16) short sA[128 * SK];
    __shared__ __align__(16) short sB[128 * SK];
    __shared__ __align__(16) float sC[2 * D2];
    int tid = threadIdx.x;
    sC[tid] = g_bncoef[tid];
    sC[tid + 256] = g_bncoef[tid + 256];
    __syncthreads();
    int r0 = blockIdx.x * 128;
    int w = tid >> 6, lane = tid & 63;
    int wr = (w >> 1) * 64, wc = (w & 1) * 64;
    int ln = lane & 15, lq = lane >> 4;
    f32x4 acc[4][4] = {};
    const uint4* gw = (const uint4*)g_w2b;
    for (int kk = 0; kk < D2; kk += BK) {
#pragma unroll
        for (int t = 0; t < 8; ++t) {
            int idx = tid + t * 256;
            int row = idx >> 4, seg = idx & 15;
            int r = r0 + row;
            int k = kk + seg * 4;
            ushort4 o = make_ushort4(0, 0, 0, 0);
            if (r < N_NODES) {
                float4 v = *(const float4*)&g_h1[(size_t)r * D2 + k];
                float4 s = *(const float4*)&sC[k];
                float4 h = *(const float4*)&sC[D2 + k];
                o.x = f2bu(fmaxf(v.x * s.x + h.x, 0.f));
                o.y = f2bu(fmaxf(v.y * s.y + h.y, 0.f));
                o.z = f2bu(fmaxf(v.z * s.z + h.z, 0.f));
                o.w = f2bu(fmaxf(v.w * s.w + h.w, 0.f));
            }
            *(ushort4*)&sA[row * SK + seg * 4] = o;
        }
#pragma unroll
        for (int t = 0; t < 4; ++t) {
            int idx = tid + t * 256;
            int row = idx >> 3, seg = idx & 7;
            *(uint4*)&sB[row * SK + seg * 8] = gw[(size_t)row * 32 + (kk >> 3) + seg];
        }
        __syncthreads();
#pragma unroll
        for (int k0 = 0; k0 < BK; k0 += 32) {
            bf16x8 af[4], bg[4];
#pragma unroll
            for (int a = 0; a < 4; ++a)
                af[a] = *(const bf16x8*)&sA[(wr + a * 16 + ln) * SK + k0 + lq * 8];
#pragma unroll
            for (int b = 0; b < 4; ++b)
                bg[b] = *(const bf16x8*)&sB[(wc + b * 16 + ln) * SK + k0 + lq * 8];
#pragma unroll
            for (int a = 0; a < 4; ++a)
#pragma unroll
                for (int b = 0; b < 4; ++b)
                    acc[a][b] = __builtin_amdgcn_mfma_f32_16x16x32_bf16(af[a], bg[b],
                                                                        acc[a][b], 0, 0, 0);
        }
        __syncthreads();
    }
#pragma unroll
    for (int a = 0; a < 4; ++a) {
#pragma unroll
        for (int r = 0; r < 4; ++r) {
            int row = r0 + wr + a * 16 + lq * 4 + r;
            if (row < N_NODES) {
#pragma unroll
                for (int b = 0; b < 4; ++b) {
                    int col = wc + b * 16 + ln;
                    float v = acc[a][b][r] + B2l[col];
                    if (LAST) out[(size_t)row * EMB + col] = v;
                    else      g_xbuf[(size_t)row * EMB + col] = fmaxf(v, 0.f);
                }
            }
        }
    }
}

extern "C" void kernel_launch(void* const* d_in, const int* in_sizes, int n_in,
                              void* d_out, int out_size, void* d_ws, size_t ws_size,
                              hipStream_t stream) {
    const float* x0 = (const float*)d_in[0];
    const float* ea = (const float*)d_in[1];
    const float* W1 = (const float*)d_in[2];
    const float* B1 = (const float*)d_in[3];
    const float* BNW = (const float*)d_in[4];
    const float* BNB = (const float*)d_in[5];
    const float* W2 = (const float*)d_in[6];
    const float* B2 = (const float*)d_in[7];
    const float* EW = (const float*)d_in[8];
    const float* EB = (const float*)d_in[9];
    const int* ei = (const int*)d_in[10];

    k_init<<<4096, 256, 0, stream>>>();
    k_edge<<<(N_EDGES * EDGE_F + 255) / 256, 256, 0, stream>>>(ei, ea);
    k_scan1<<<NSCB, 1024, 0, stream>>>();
    k_scan2<<<1, 128, 0, stream>>>();
    k_scan3<<<(N_NODES + 255) / 256, 256, 0, stream>>>();
    k_fill<<<(N_EDGES + 255) / 256, 256, 0, stream>>>(ei);

    const int GB = (N_NODES + 127) / 128;   // 782
    for (int l = 0; l < 5; ++l) {
        const float* W1l = W1 + (size_t)l * D2 * D2;
        const float* B1l = B1 + (size_t)l * D2;
        const float* BNWl = BNW + (size_t)l * D2;
        const float* BNBl = BNB + (size_t)l * D2;
        const float* W2l = W2 + (size_t)l * EMB * D2;
        const float* B2l = B2 + (size_t)l * EMB;
        const float* EWl = EW + (size_t)l * EMB * EDGE_F;
        const float* EBl = EB + (size_t)l * EMB;

        k_cvt<<<(D2 * D2 + EMB * D2 + 255) / 256, 256, 0, stream>>>(W1l, W2l);

        if (l == 0)
            k_agg<true><<<N_NODES / 8, 256, 0, stream>>>(x0, EWl, EBl);
        else
            k_agg<false><<<N_NODES / 8, 256, 0, stream>>>(nullptr, EWl, EBl);

        k_gemm1<<<dim3(GB, 2), 256, 0, stream>>>(B1l);
        k_bnfin<<<1, 256, 0, stream>>>(BNWl, BNBl);

        if (l < 4)
            k_gemm2<false><<<dim3(GB, 1), 256, 0, stream>>>(B2l, nullptr);
        else
            k_gemm2<true><<<dim3(GB, 1), 256, 0, stream>>>(B2l, (float*)d_out);
    }
}